// Round 13
// baseline (194.863 us; speedup 1.0000x reference)
//
#include <hip/hip_runtime.h>
#include <math.h>

namespace {
constexpr int NIN   = 32;
constexpr int H_    = 14;
constexpr int CIN   = 8;
constexpr int C_    = 32;
constexpr int COUT  = 16;
constexpr int R_    = 288;
constexpr int W_    = 12;
constexpr int NITER = 3;
constexpr int CH    = 32;              // r per chunk
constexpr int NCH   = 9;               // 288/32
constexpr size_t XSUB = (size_t)NIN * H_ * H_ * CIN;   // x stride per batch elem
}

typedef unsigned int u32;
typedef const __attribute__((address_space(1))) u32* as1_u32p;
typedef __attribute__((address_space(3))) u32* as3_u32p;

__device__ __forceinline__ void async_copy16(const void* g, void* l) {
    __builtin_amdgcn_global_load_lds((as1_u32p)g, (as3_u32p)l, 16, 0, 0);
}
__device__ __forceinline__ float dot4(const float4 a, const float4 b) {
    return fmaf(a.x, b.x, fmaf(a.y, b.y, fmaf(a.z, b.z, a.w * b.w)));
}
// VALU-pipe cross-lane ops (DPP) — keep traffic off the DS pipe.
// quad_perm[a,b,c,d] ctrl = a|(b<<2)|(c<<4)|(d<<6); row_shr:N = 0x110|N.
__device__ __forceinline__ float dpp_add_xor1(float v) {
    int t = __builtin_amdgcn_update_dpp(0, __float_as_int(v), 0xB1, 0xF, 0xF, true);
    return v + __int_as_float(t);
}
__device__ __forceinline__ float dpp_add_xor2(float v) {
    int t = __builtin_amdgcn_update_dpp(0, __float_as_int(v), 0x4E, 0xF, 0xF, true);
    return v + __int_as_float(t);
}
__device__ __forceinline__ float dpp_add_shr4(float v) {
    int t = __builtin_amdgcn_update_dpp(0, __float_as_int(v), 0x114, 0xF, 0xF, true);
    return v + __int_as_float(t);
}
__device__ __forceinline__ float dpp_add_shr8(float v) {
    int t = __builtin_amdgcn_update_dpp(0, __float_as_int(v), 0x118, 0xF, 0xF, true);
    return v + __int_as_float(t);
}
template <int CTRL>
__device__ __forceinline__ float dpp_bc(float v) {   // quad broadcast (mov)
    return __int_as_float(
        __builtin_amdgcn_update_dpp(0, __float_as_int(v), CTRL, 0xF, 0xF, true));
}

// One block (256 thr) per (c, b-QUAD, p, q) — R12 structure. Change vs R12:
// routing scratch (sRed/redE/vS, ~800 B) OVERLAYS wbuf — total LDS exactly
// 32768 B -> 5 blocks/CU (R12's 33792 B capped occupancy at 4 blocks; LDS
// was the binding occupancy limit, VGPR=84 allows 6 waves/SIMD). One extra
// barrier after the priors loop makes the overlay safe (chunk 8 reads
// wbuf[0], which the routing arrays alias).
//  x path: per chunk each lane loads ONE float4 from global; og-quad
//  exchanges via 16 quad_perm broadcasts (VALU) — R12. s/se reductions:
//  bits 2-3 on DPP row_shr, 4-5 on swizzle — R11/R12.
// Lessons: 256-thr blocks (512 regressed: R6,R10); no forced waves/EU (R4
// spill); MLP in zero-VGPR global_load_lds queue (R7); priors fp32 (R2).
__global__ __launch_bounds__(256)
void caps_routeD(const float* __restrict__ x,
                 const float* __restrict__ rw,
                 float* __restrict__ out)
{
    __shared__ __align__(16) char smem[2 * 1024 * 16];   // 32768 B exactly

    float4* wbuf0 = (float4*)smem;             // [1024] buf 0
    float4* wbuf1 = (float4*)smem + 1024;      // [1024] buf 1
    // routing-phase overlay (valid only after the post-priors barrier):
    float* sRedp = (float*)smem;               // [4][2][16]  512 B
    float* redEp = (float*)(smem + 512);       // [4][2]       32 B
    float* vSp   = (float*)(smem + 544);       // [4][16]     256 B

    const int tid = threadIdx.x;
    const int p  = blockIdx.x / W_;
    const int q  = blockIdx.x % W_;
    const int b0 = blockIdx.y * 4;
    const int c  = blockIdx.z;

    const int og   = tid & 3;
    const int rl   = tid >> 2;     // 0..63
    const int cr   = rl & 31;      // chunk-local r
    const int sh   = rl >> 5;      // wave-uniform
    const int lane = tid & 63;
    const int wv   = tid >> 6;
    const int sA   = sh * 2;       // first sub of this thread's pair

    // per-lane x base: lane og covers (sub sA + (og>>1), float4-half og&1)
    const float* xq = x + (size_t)(b0 + sA + (og >> 1)) * XSUB + (og & 1) * 4;
    const float4* rwcF4 = (const float4*)(rw + (size_t)c * R_ * CIN * COUT);

    float4 xv;                     // this lane's single x float4 for cur chunk
    auto xld = [&](int k) {
        const int r  = k * CH + cr;
        const int n  = r / 9, rem = r - n * 9;
        const int kh = rem / 3, kw = rem - kh * 3;
        xv = *(const float4*)(xq + ((n * H_ + (p + kh)) * H_ + (q + kw)) * CIN);
    };

    auto stage = [&](int k, float4* buf) {
        // slot s = t*256+tid -> [ii=s>>7][wcr=(s>>2)&31][wog=s&3];
        // global f4 = wcr*32 + ii*4 + wog (chunk base k*1024 f4)
        const float4* gchunk = rwcF4 + (size_t)k * (CH * 32);
        #pragma unroll
        for (int t = 0; t < 4; ++t) {
            const int s   = t * 256 + tid;
            const int ii  = s >> 7;
            const int wcr = (s >> 2) & 31;
            async_copy16(gchunk + (wcr * 32 + ii * 4 + (s & 3)),
                         (char*)buf + (t * 256 + (tid & 192)) * 16);
        }
    };

    float4 acc[NCH][2];

    xld(0);
    stage(0, wbuf0);
    #pragma unroll
    for (int k = 0; k < NCH; ++k) {
        __syncthreads();               // stage(k)+xld(k) drained; other buf free
        if (k + 1 < NCH) stage(k + 1, ((k + 1) & 1) ? wbuf1 : wbuf0);
        const float4* wb = (k & 1) ? wbuf1 : wbuf0;
        // og-quad exchange: fA = sub sA floats 0..7, fB = sub sA+1 (VALU)
        const float4 cur = xv;
        float fA[8], fB[8];
        fA[0] = dpp_bc<0x00>(cur.x); fA[1] = dpp_bc<0x00>(cur.y);
        fA[2] = dpp_bc<0x00>(cur.z); fA[3] = dpp_bc<0x00>(cur.w);
        fA[4] = dpp_bc<0x55>(cur.x); fA[5] = dpp_bc<0x55>(cur.y);
        fA[6] = dpp_bc<0x55>(cur.z); fA[7] = dpp_bc<0x55>(cur.w);
        fB[0] = dpp_bc<0xAA>(cur.x); fB[1] = dpp_bc<0xAA>(cur.y);
        fB[2] = dpp_bc<0xAA>(cur.z); fB[3] = dpp_bc<0xAA>(cur.w);
        fB[4] = dpp_bc<0xFF>(cur.x); fB[5] = dpp_bc<0xFF>(cur.y);
        fB[6] = dpp_bc<0xFF>(cur.z); fB[7] = dpp_bc<0xFF>(cur.w);
        if (k + 1 < NCH) xld(k + 1);   // WAR on xv cleared (cur extracted)
        float4 a0 = make_float4(0.f, 0.f, 0.f, 0.f);
        float4 a1 = make_float4(0.f, 0.f, 0.f, 0.f);
        #pragma unroll
        for (int i = 0; i < 8; ++i) {
            const float4 wv4 = wb[i * 128 + cr * 4 + og];   // conflict-free b128
            a0.x = fmaf(fA[i], wv4.x, a0.x);  a1.x = fmaf(fB[i], wv4.x, a1.x);
            a0.y = fmaf(fA[i], wv4.y, a0.y);  a1.y = fmaf(fB[i], wv4.y, a1.y);
            a0.z = fmaf(fA[i], wv4.z, a0.z);  a1.z = fmaf(fB[i], wv4.z, a1.z);
            a0.w = fmaf(fA[i], wv4.w, a0.w);  a1.w = fmaf(fB[i], wv4.w, a1.w);
        }
        acc[k][0] = a0;  acc[k][1] = a1;
    }
    __syncthreads();   // all wbuf reads done -> overlay region safe to reuse

    float lgA[NCH], lgB[NCH];
    #pragma unroll
    for (int j = 0; j < NCH; ++j) { lgA[j] = 0.f; lgB[j] = 0.f; }

    for (int it = 0; it < NITER; ++it) {
        float4 s0 = make_float4(0.f, 0.f, 0.f, 0.f);
        float4 s1 = make_float4(0.f, 0.f, 0.f, 0.f);
        float se0 = 0.f, se1 = 0.f;

        if (it == 0) {
            #pragma unroll
            for (int j = 0; j < NCH; ++j) {
                s0.x += acc[j][0].x;  s1.x += acc[j][1].x;
                s0.y += acc[j][0].y;  s1.y += acc[j][1].y;
                s0.z += acc[j][0].z;  s1.z += acc[j][1].z;
                s0.w += acc[j][0].w;  s1.w += acc[j][1].w;
            }
        } else {
            const float4 v0 = *(const float4*)&vSp[sA * 16 + og * 4];
            const float4 v1 = *(const float4*)&vSp[(sA + 1) * 16 + og * 4];
            #pragma unroll
            for (int j = 0; j < NCH; ++j) {
                float d0 = dot4(acc[j][0], v0);
                float d1 = dot4(acc[j][1], v1);
                d0 = dpp_add_xor1(d0);  d1 = dpp_add_xor1(d1);   // VALU
                d0 = dpp_add_xor2(d0);  d1 = dpp_add_xor2(d1);
                lgA[j] += d0;                 lgB[j] += d1;
                const float e0 = __expf(lgA[j]);
                const float e1 = __expf(lgB[j]);
                se0 += e0;                    se1 += e1;
                s0.x = fmaf(e0, acc[j][0].x, s0.x);  s1.x = fmaf(e1, acc[j][1].x, s1.x);
                s0.y = fmaf(e0, acc[j][0].y, s0.y);  s1.y = fmaf(e1, acc[j][1].y, s1.y);
                s0.z = fmaf(e0, acc[j][0].z, s0.z);  s1.z = fmaf(e1, acc[j][1].z, s1.z);
                s0.w = fmaf(e0, acc[j][0].w, s0.w);  s1.w = fmaf(e1, acc[j][1].w, s1.w);
            }
            // se: og-redundant; lane bits 2-3 on DPP, 4-5 on swizzle
            se0 = dpp_add_shr4(se0);  se1 = dpp_add_shr4(se1);
            se0 = dpp_add_shr8(se0);  se1 = dpp_add_shr8(se1);
            se0 += __shfl_xor(se0, 16, 64);  se1 += __shfl_xor(se1, 16, 64);
            se0 += __shfl_xor(se0, 32, 64);  se1 += __shfl_xor(se1, 32, 64);
            if (lane == 15) { redEp[wv * 2 + 0] = se0; redEp[wv * 2 + 1] = se1; }
        }

        // s-reduce: bits 2-3 via DPP row_shr (og-preserving; totals in lanes
        // 12..15), bits 4-5 via swizzle.
        s0.x = dpp_add_shr4(s0.x);  s1.x = dpp_add_shr4(s1.x);
        s0.y = dpp_add_shr4(s0.y);  s1.y = dpp_add_shr4(s1.y);
        s0.z = dpp_add_shr4(s0.z);  s1.z = dpp_add_shr4(s1.z);
        s0.w = dpp_add_shr4(s0.w);  s1.w = dpp_add_shr4(s1.w);
        s0.x = dpp_add_shr8(s0.x);  s1.x = dpp_add_shr8(s1.x);
        s0.y = dpp_add_shr8(s0.y);  s1.y = dpp_add_shr8(s1.y);
        s0.z = dpp_add_shr8(s0.z);  s1.z = dpp_add_shr8(s1.z);
        s0.w = dpp_add_shr8(s0.w);  s1.w = dpp_add_shr8(s1.w);
        #pragma unroll
        for (int off = 16; off <= 32; off <<= 1) {
            s0.x += __shfl_xor(s0.x, off, 64);  s1.x += __shfl_xor(s1.x, off, 64);
            s0.y += __shfl_xor(s0.y, off, 64);  s1.y += __shfl_xor(s1.y, off, 64);
            s0.z += __shfl_xor(s0.z, off, 64);  s1.z += __shfl_xor(s1.z, off, 64);
            s0.w += __shfl_xor(s0.w, off, 64);  s1.w += __shfl_xor(s1.w, off, 64);
        }
        if (lane >= 12 && lane < 16) {   // lanes 12..15, og = lane&3
            *(float4*)&sRedp[wv * 32 + 0 * 16 + (lane & 3) * 4] = s0;
            *(float4*)&sRedp[wv * 32 + 1 * 16 + (lane & 3) * 4] = s1;
        }
        __syncthreads();

        // ---- squash: 64 threads = (sub 0..3, o 0..15)
        if (tid < 64) {
            const int sub = tid >> 4;
            const int o   = tid & 15;
            const int g   = sub >> 1;      // wave-pair group
            const int l   = sub & 1;       // local sub within pair
            const float inv = (it == 0)
                ? (1.0f / (float)R_)
                : 1.0f / (redEp[(g * 2) * 2 + l] + redEp[(g * 2 + 1) * 2 + l]);
            float s = (sRedp[(g * 2) * 32 + l * 16 + o]
                     + sRedp[(g * 2 + 1) * 32 + l * 16 + o]) * inv;
            float sn = s * s;
            sn = dpp_add_xor1(sn);
            sn = dpp_add_xor2(sn);
            sn += __shfl_xor(sn, 4, 64);
            sn += __shfl_xor(sn, 8, 64);
            const float v = s * (sqrtf(sn) / (1.0f + sn));
            if (it == NITER - 1) {
                out[((((size_t)(b0 + sub) * C_ + c) * W_ + p) * W_ + q) * COUT + o] = v;
            } else {
                vSp[sub * 16 + o] = v;
            }
        }
        if (it == NITER - 1) break;
        __syncthreads();   // vS visible before next iteration
    }
}

extern "C" void kernel_launch(void* const* d_in, const int* in_sizes, int n_in,
                              void* d_out, int out_size, void* d_ws, size_t ws_size,
                              hipStream_t stream) {
    const float* x  = (const float*)d_in[0];
    const float* rw = (const float*)d_in[1];
    float* out = (float*)d_out;
    dim3 grid(W_ * W_, 2, C_);
    caps_routeD<<<grid, 256, 0, stream>>>(x, rw, out);
}

// Round 14
// 194.083 us; speedup vs baseline: 1.0040x; 1.0040x over previous
//
#include <hip/hip_runtime.h>
#include <math.h>

namespace {
constexpr int NIN   = 32;
constexpr int H_    = 14;
constexpr int CIN   = 8;
constexpr int C_    = 32;
constexpr int COUT  = 16;
constexpr int R_    = 288;
constexpr int W_    = 12;
constexpr int NITER = 3;
constexpr int CH    = 32;              // r per chunk
constexpr int NCH   = 9;               // 288/32
constexpr size_t XSUB = (size_t)NIN * H_ * H_ * CIN;   // x stride per batch elem
}

typedef unsigned int u32;
typedef const __attribute__((address_space(1))) u32* as1_u32p;
typedef __attribute__((address_space(3))) u32* as3_u32p;

__device__ __forceinline__ void async_copy16(const void* g, void* l) {
    __builtin_amdgcn_global_load_lds((as1_u32p)g, (as3_u32p)l, 16, 0, 0);
}
__device__ __forceinline__ float dot4(const float4 a, const float4 b) {
    return fmaf(a.x, b.x, fmaf(a.y, b.y, fmaf(a.z, b.z, a.w * b.w)));
}
// VALU-pipe cross-lane ops (DPP) — keep traffic off the DS pipe.
// quad_perm[a,b,c,d] ctrl = a|(b<<2)|(c<<4)|(d<<6); row_shr:N = 0x110|N.
__device__ __forceinline__ float dpp_add_xor1(float v) {
    int t = __builtin_amdgcn_update_dpp(0, __float_as_int(v), 0xB1, 0xF, 0xF, true);
    return v + __int_as_float(t);
}
__device__ __forceinline__ float dpp_add_xor2(float v) {
    int t = __builtin_amdgcn_update_dpp(0, __float_as_int(v), 0x4E, 0xF, 0xF, true);
    return v + __int_as_float(t);
}
__device__ __forceinline__ float dpp_add_shr4(float v) {
    int t = __builtin_amdgcn_update_dpp(0, __float_as_int(v), 0x114, 0xF, 0xF, true);
    return v + __int_as_float(t);
}
__device__ __forceinline__ float dpp_add_shr8(float v) {
    int t = __builtin_amdgcn_update_dpp(0, __float_as_int(v), 0x118, 0xF, 0xF, true);
    return v + __int_as_float(t);
}
template <int CTRL>
__device__ __forceinline__ float dpp_bc(float v) {   // quad broadcast (mov)
    return __int_as_float(
        __builtin_amdgcn_update_dpp(0, __float_as_int(v), CTRL, 0xF, 0xF, true));
}

// One block (256 thr) per (c, b-QUAD, p, q) — R12 base. Changes:
//  (1) W split across pipes: i=0..3 staged via global_load_lds (8 KB/buf,
//      double-buffered), i=4..7 read DIRECT from global into 4 registers,
//      prefetched one chunk ahead (coalesced dwordx4; the 2x sh-redundancy
//      lands on L1/L2, which has slack — DS was the binding pipe at ~65%
//      of its 99 us floor). Halves both W ds_reads and staging writes.
//  (2) Routing: ONE barrier per iteration. After the wave-partial sRed/redE
//      write + barrier, every thread redundantly computes inv, s-slice,
//      sn (in-quad DPP butterfly), coef, v into REGISTERS — removes the vS
//      broadcast barrier, the 64-thread serial squash, and vS itself.
//      Iteration WAR handled by double-buffered scratch, not barriers.
// Lessons: 256-thr blocks (512 regressed: R6,R10); no forced waves/EU (R4
// spill); priors fp32 (R2); cross-lane on DPP (R9/R11); non-redundant
// global x via quad exchange (R12).
__global__ __launch_bounds__(256)
void caps_routeE(const float* __restrict__ x,
                 const float* __restrict__ rw,
                 float* __restrict__ out)
{
    __shared__ __align__(16) float4 wbuf[2][512];   // [buf][i(4)][cr(32)][og(4)] 8 KB each
    __shared__ __align__(16) float  sRed[2][4][2][16];  // [iter-buf][wave][lsub][o]
    __shared__ float  redE[2][4][2];                    // [iter-buf][wave][lsub]

    const int tid = threadIdx.x;
    const int p  = blockIdx.x / W_;
    const int q  = blockIdx.x % W_;
    const int b0 = blockIdx.y * 4;
    const int c  = blockIdx.z;

    const int og   = tid & 3;
    const int rl   = tid >> 2;     // 0..63
    const int cr   = rl & 31;      // chunk-local r
    const int sh   = rl >> 5;      // wave-uniform: waves 0,1 -> subs 0,1; 2,3 -> 2,3
    const int lane = tid & 63;
    const int wv   = tid >> 6;
    const int sA   = sh * 2;       // first sub of this thread's pair (== wave pair base)

    // per-lane x base: lane og covers (sub sA + (og>>1), float4-half og&1)
    const float* xq = x + (size_t)(b0 + sA + (og >> 1)) * XSUB + (og & 1) * 4;
    const float4* rwcF4 = (const float4*)(rw + (size_t)c * R_ * CIN * COUT);
    const float4* wgbase = rwcF4 + cr * 32 + og;   // + k*1024 + i*4

    float4 xv;                     // this lane's single x float4 for cur chunk
    auto xld = [&](int k) {
        const int r  = k * CH + cr;
        const int n  = r / 9, rem = r - n * 9;
        const int kh = rem / 3, kw = rem - kh * 3;
        xv = *(const float4*)(xq + ((n * H_ + (p + kh)) * H_ + (q + kw)) * CIN);
    };

    float4 gw0, gw1, gw2, gw3;     // W i=4..7 for cur chunk (direct-global half)
    auto wld = [&](int k) {
        const float4* g = wgbase + (size_t)k * 1024;
        gw0 = g[16]; gw1 = g[20]; gw2 = g[24]; gw3 = g[28];
    };

    auto stage = [&](int k, int buf) {   // i = 0..3 half -> LDS
        // slot s = t*256+tid -> [ii=s>>7][wcr=(s>>2)&31][wog=s&3];
        // global f4 = wcr*32 + ii*4 + wog (chunk base k*1024 f4)
        const float4* gchunk = rwcF4 + (size_t)k * (CH * 32);
        #pragma unroll
        for (int t = 0; t < 2; ++t) {
            const int s   = t * 256 + tid;
            const int ii  = s >> 7;
            const int wcr = (s >> 2) & 31;
            async_copy16(gchunk + (wcr * 32 + ii * 4 + (s & 3)),
                         (char*)&wbuf[buf][0] + (t * 256 + (tid & 192)) * 16);
        }
    };

    float4 acc[NCH][2];

    xld(0); wld(0); stage(0, 0);
    #pragma unroll
    for (int k = 0; k < NCH; ++k) {
        __syncthreads();               // stage(k)+xld(k)+wld(k) drained; other buf free
        if (k + 1 < NCH) stage(k + 1, (k + 1) & 1);
        const float4* wb = &wbuf[k & 1][0];
        // og-quad exchange: fA = sub sA channels 0..7, fB = sub sA+1 (VALU)
        const float4 cur = xv;
        float fA[8], fB[8];
        fA[0] = dpp_bc<0x00>(cur.x); fA[1] = dpp_bc<0x00>(cur.y);
        fA[2] = dpp_bc<0x00>(cur.z); fA[3] = dpp_bc<0x00>(cur.w);
        fA[4] = dpp_bc<0x55>(cur.x); fA[5] = dpp_bc<0x55>(cur.y);
        fA[6] = dpp_bc<0x55>(cur.z); fA[7] = dpp_bc<0x55>(cur.w);
        fB[0] = dpp_bc<0xAA>(cur.x); fB[1] = dpp_bc<0xAA>(cur.y);
        fB[2] = dpp_bc<0xAA>(cur.z); fB[3] = dpp_bc<0xAA>(cur.w);
        fB[4] = dpp_bc<0xFF>(cur.x); fB[5] = dpp_bc<0xFF>(cur.y);
        fB[6] = dpp_bc<0xFF>(cur.z); fB[7] = dpp_bc<0xFF>(cur.w);
        if (k + 1 < NCH) xld(k + 1);   // WAR on xv cleared (cur extracted)

        float4 a0 = make_float4(0.f, 0.f, 0.f, 0.f);
        float4 a1 = make_float4(0.f, 0.f, 0.f, 0.f);
        // i = 4..7 from direct-global registers
        {
            const float4 g0 = gw0, g1 = gw1, g2 = gw2, g3 = gw3;
            if (k + 1 < NCH) wld(k + 1);   // WAR on gw cleared
            a0.x = fmaf(fA[4], g0.x, a0.x);  a1.x = fmaf(fB[4], g0.x, a1.x);
            a0.y = fmaf(fA[4], g0.y, a0.y);  a1.y = fmaf(fB[4], g0.y, a1.y);
            a0.z = fmaf(fA[4], g0.z, a0.z);  a1.z = fmaf(fB[4], g0.z, a1.z);
            a0.w = fmaf(fA[4], g0.w, a0.w);  a1.w = fmaf(fB[4], g0.w, a1.w);
            a0.x = fmaf(fA[5], g1.x, a0.x);  a1.x = fmaf(fB[5], g1.x, a1.x);
            a0.y = fmaf(fA[5], g1.y, a0.y);  a1.y = fmaf(fB[5], g1.y, a1.y);
            a0.z = fmaf(fA[5], g1.z, a0.z);  a1.z = fmaf(fB[5], g1.z, a1.z);
            a0.w = fmaf(fA[5], g1.w, a0.w);  a1.w = fmaf(fB[5], g1.w, a1.w);
            a0.x = fmaf(fA[6], g2.x, a0.x);  a1.x = fmaf(fB[6], g2.x, a1.x);
            a0.y = fmaf(fA[6], g2.y, a0.y);  a1.y = fmaf(fB[6], g2.y, a1.y);
            a0.z = fmaf(fA[6], g2.z, a0.z);  a1.z = fmaf(fB[6], g2.z, a1.z);
            a0.w = fmaf(fA[6], g2.w, a0.w);  a1.w = fmaf(fB[6], g2.w, a1.w);
            a0.x = fmaf(fA[7], g3.x, a0.x);  a1.x = fmaf(fB[7], g3.x, a1.x);
            a0.y = fmaf(fA[7], g3.y, a0.y);  a1.y = fmaf(fB[7], g3.y, a1.y);
            a0.z = fmaf(fA[7], g3.z, a0.z);  a1.z = fmaf(fB[7], g3.z, a1.z);
            a0.w = fmaf(fA[7], g3.w, a0.w);  a1.w = fmaf(fB[7], g3.w, a1.w);
        }
        // i = 0..3 from LDS
        #pragma unroll
        for (int i = 0; i < 4; ++i) {
            const float4 wv4 = wb[i * 128 + cr * 4 + og];   // conflict-free b128
            a0.x = fmaf(fA[i], wv4.x, a0.x);  a1.x = fmaf(fB[i], wv4.x, a1.x);
            a0.y = fmaf(fA[i], wv4.y, a0.y);  a1.y = fmaf(fB[i], wv4.y, a1.y);
            a0.z = fmaf(fA[i], wv4.z, a0.z);  a1.z = fmaf(fB[i], wv4.z, a1.z);
            a0.w = fmaf(fA[i], wv4.w, a0.w);  a1.w = fmaf(fB[i], wv4.w, a1.w);
        }
        acc[k][0] = a0;  acc[k][1] = a1;
    }

    float lgA[NCH], lgB[NCH];
    #pragma unroll
    for (int j = 0; j < NCH; ++j) { lgA[j] = 0.f; lgB[j] = 0.f; }

    float4 v0, v1;   // squashed v for this thread's sub pair (og-slice), in regs

    for (int it = 0; it < NITER; ++it) {
        float4 s0 = make_float4(0.f, 0.f, 0.f, 0.f);
        float4 s1 = make_float4(0.f, 0.f, 0.f, 0.f);
        float se0 = 0.f, se1 = 0.f;

        if (it == 0) {
            #pragma unroll
            for (int j = 0; j < NCH; ++j) {
                s0.x += acc[j][0].x;  s1.x += acc[j][1].x;
                s0.y += acc[j][0].y;  s1.y += acc[j][1].y;
                s0.z += acc[j][0].z;  s1.z += acc[j][1].z;
                s0.w += acc[j][0].w;  s1.w += acc[j][1].w;
            }
        } else {
            #pragma unroll
            for (int j = 0; j < NCH; ++j) {
                float d0 = dot4(acc[j][0], v0);
                float d1 = dot4(acc[j][1], v1);
                d0 = dpp_add_xor1(d0);  d1 = dpp_add_xor1(d1);   // VALU
                d0 = dpp_add_xor2(d0);  d1 = dpp_add_xor2(d1);
                lgA[j] += d0;                 lgB[j] += d1;
                const float e0 = __expf(lgA[j]);
                const float e1 = __expf(lgB[j]);
                se0 += e0;                    se1 += e1;
                s0.x = fmaf(e0, acc[j][0].x, s0.x);  s1.x = fmaf(e1, acc[j][1].x, s1.x);
                s0.y = fmaf(e0, acc[j][0].y, s0.y);  s1.y = fmaf(e1, acc[j][1].y, s1.y);
                s0.z = fmaf(e0, acc[j][0].z, s0.z);  s1.z = fmaf(e1, acc[j][1].z, s1.z);
                s0.w = fmaf(e0, acc[j][0].w, s0.w);  s1.w = fmaf(e1, acc[j][1].w, s1.w);
            }
            // se: og-redundant; lane bits 2-3 on DPP, 4-5 on swizzle
            se0 = dpp_add_shr4(se0);  se1 = dpp_add_shr4(se1);
            se0 = dpp_add_shr8(se0);  se1 = dpp_add_shr8(se1);
            se0 += __shfl_xor(se0, 16, 64);  se1 += __shfl_xor(se1, 16, 64);
            se0 += __shfl_xor(se0, 32, 64);  se1 += __shfl_xor(se1, 32, 64);
        }

        // s-reduce over the wave's 16 cr-slots: bits 2-3 via DPP row_shr
        // (og-preserving; totals in lanes 12..15), bits 4-5 via swizzle.
        s0.x = dpp_add_shr4(s0.x);  s1.x = dpp_add_shr4(s1.x);
        s0.y = dpp_add_shr4(s0.y);  s1.y = dpp_add_shr4(s1.y);
        s0.z = dpp_add_shr4(s0.z);  s1.z = dpp_add_shr4(s1.z);
        s0.w = dpp_add_shr4(s0.w);  s1.w = dpp_add_shr4(s1.w);
        s0.x = dpp_add_shr8(s0.x);  s1.x = dpp_add_shr8(s1.x);
        s0.y = dpp_add_shr8(s0.y);  s1.y = dpp_add_shr8(s1.y);
        s0.z = dpp_add_shr8(s0.z);  s1.z = dpp_add_shr8(s1.z);
        s0.w = dpp_add_shr8(s0.w);  s1.w = dpp_add_shr8(s1.w);
        #pragma unroll
        for (int off = 16; off <= 32; off <<= 1) {
            s0.x += __shfl_xor(s0.x, off, 64);  s1.x += __shfl_xor(s1.x, off, 64);
            s0.y += __shfl_xor(s0.y, off, 64);  s1.y += __shfl_xor(s1.y, off, 64);
            s0.z += __shfl_xor(s0.z, off, 64);  s1.z += __shfl_xor(s1.z, off, 64);
            s0.w += __shfl_xor(s0.w, off, 64);  s1.w += __shfl_xor(s1.w, off, 64);
        }
        const int ib = it & 1;           // double-buffered scratch: no WAR barrier
        if (lane >= 12 && lane < 16) {   // lanes 12..15, og = lane&3
            *(float4*)&sRed[ib][wv][0][(lane & 3) * 4] = s0;
            *(float4*)&sRed[ib][wv][1][(lane & 3) * 4] = s1;
        }
        if (it && lane == 15) { redE[ib][wv][0] = se0; redE[ib][wv][1] = se1; }
        __syncthreads();                 // the ONLY barrier this iteration

        // ---- every thread: inv, s-slice, sn (quad butterfly), coef, v
        // wave pair holding subs {sA, sA+1} is waves {sA, sA+1} (sA = 2*sh).
        const float4 pA0 = *(const float4*)&sRed[ib][sA][0][og * 4];
        const float4 pB0 = *(const float4*)&sRed[ib][sA + 1][0][og * 4];
        const float4 pA1 = *(const float4*)&sRed[ib][sA][1][og * 4];
        const float4 pB1 = *(const float4*)&sRed[ib][sA + 1][1][og * 4];
        float inv0, inv1;
        if (it == 0) {
            inv0 = inv1 = 1.0f / (float)R_;
        } else {
            inv0 = 1.0f / (redE[ib][sA][0] + redE[ib][sA + 1][0]);
            inv1 = 1.0f / (redE[ib][sA][1] + redE[ib][sA + 1][1]);
        }
        float4 ss0, ss1;
        ss0.x = (pA0.x + pB0.x) * inv0;  ss1.x = (pA1.x + pB1.x) * inv1;
        ss0.y = (pA0.y + pB0.y) * inv0;  ss1.y = (pA1.y + pB1.y) * inv1;
        ss0.z = (pA0.z + pB0.z) * inv0;  ss1.z = (pA1.z + pB1.z) * inv1;
        ss0.w = (pA0.w + pB0.w) * inv0;  ss1.w = (pA1.w + pB1.w) * inv1;
        float sn0 = dot4(ss0, ss0);
        float sn1 = dot4(ss1, ss1);
        sn0 = dpp_add_xor1(sn0);  sn1 = dpp_add_xor1(sn1);
        sn0 = dpp_add_xor2(sn0);  sn1 = dpp_add_xor2(sn1);
        const float c0 = sqrtf(sn0) / (1.0f + sn0);
        const float c1 = sqrtf(sn1) / (1.0f + sn1);
        v0.x = ss0.x * c0;  v1.x = ss1.x * c1;
        v0.y = ss0.y * c0;  v1.y = ss1.y * c1;
        v0.z = ss0.z * c0;  v1.z = ss1.z * c1;
        v0.w = ss0.w * c0;  v1.w = ss1.w * c1;

        if (it == NITER - 1) {
            // store: waves 0,2 / cr in {0,1}: sub = sA + cr, slice og
            if (cr < 2) {
                const float4 vv = cr ? v1 : v0;
                *(float4*)&out[((((size_t)(b0 + sA + cr) * C_ + c) * W_ + p) * W_ + q)
                               * COUT + og * 4] = vv;
            }
            break;
        }
        // no second barrier: next iter writes the other scratch buffer, and
        // the following barrier orders buf reuse (see WAR analysis).
    }
}

extern "C" void kernel_launch(void* const* d_in, const int* in_sizes, int n_in,
                              void* d_out, int out_size, void* d_ws, size_t ws_size,
                              hipStream_t stream) {
    const float* x  = (const float*)d_in[0];
    const float* rw = (const float*)d_in[1];
    float* out = (float*)d_out;
    dim3 grid(W_ * W_, 2, C_);
    caps_routeE<<<grid, 256, 0, stream>>>(x, rw, out);
}